// Round 10
// baseline (389.713 us; speedup 1.0000x reference)
//
#include <hip/hip_runtime.h>

// SSIM loss, fused single pass, barrier-free, spill-free.
// [32,3,512,512] fp32 = 96 planes of 512x512.
// Round-15: round-10 phase body EXACTLY (best verified: 125us, absmax 0.0)
// + geometry change only: 64x32 tiles (was 64x64) to add resident waves.
// Rationale (round-10 counters): wall 3900cy/phase/SIMD; per-wave VALU
// ~470cy, critical path ~650cy -> issue NOT saturated (6x470 < 3900); the
// kernel is WAVE-STARVED and grid=1536 gave exactly 6 blocks/CU lifetime,
// so only smaller tiles can add waves. Now: 12288 tiles, 2-wave 128-thread
// blocks (6144 blocks = 24/CU lifetime), LDS 10.25KB/block -> 15 resident
// blocks/CU = 30 waves/CU = 7.5/SIMD (vs 6). Work +9% (42 phases per 32
// rows vs 77 per 64), util 0.72 -> ~0.9.
// Phase body (round-10): 8-slot LDS ring, distance-5 prefetch, s_waitcnt
// vmcnt(10) (never 0), global_load_lds dwordx4 per-lane addr + uniform LDS
// dest, merged p|t slot (ds_read2 pairs at +0/+80), pk dual-f32 math,
// EXACT round-3 per-pixel arithmetic.

#define IMG_H   512
#define IMG_W   512
#define TH      32          // tile rows per wave (64 cols per wave)
#define LROW    160         // floats per LDS row-slot: p[0..79] | t[80..159]
#define RING    8           // ring slots (rows j..j+5 live)
#define SSIM_C1 1e-4f
#define SSIM_C2 9e-4f

typedef float v2f __attribute__((ext_vector_type(2)));

// Gaussian taps, sigma=1.5, window 11.
__device__ constexpr float G[11] = {
    0.00102838f, 0.00759879f, 0.03600078f, 0.10936070f, 0.21300563f,
    0.26601180f,
    0.21300563f, 0.10936070f, 0.03600078f, 0.00759879f, 0.00102838f
};

// Async 16B/lane global->LDS. Global addr is per-lane; LDS dest is
// wave-uniform base + lane*16 (m97/m104).
__device__ __forceinline__ void gload16(const float* g, float* l) {
    __builtin_amdgcn_global_load_lds(
        (const __attribute__((address_space(1))) float*)g,
        (__attribute__((address_space(3))) float*)l, 16, 0, 0);
}

template<int PH>
__device__ __forceinline__ void phase(const float* __restrict__ pplw,
                                      const float* __restrict__ tplw,
                                      int r0, int j0, int lane4,
                                      float (*B)[LROW],
                                      int lane, bool lv,
                                      v2f (&acc01)[11], v2f (&acc23)[11],
                                      float (&accpt)[11], float& lsum) {
    const int j = j0 + PH;

    // ---- issue async dwordx4 loads for row j+5 into ring slot (j+5)&7 ----
    // Row clamped so EVERY phase issues exactly 2 VMEM ops (vmcnt arithmetic
    // exact); clamped-row garbage never read (row-OOB phases skip conv).
    {
        const int rg  = r0 + j;                   // = (r0-5) + (j+5)
        const int rgc = min(max(rg, 0), IMG_H - 1);
        const int sI  = (j + 5) & (RING - 1);
        const float* ps = pplw + (size_t)rgc * IMG_W + lane4;  // per-lane
        const float* ts = tplw + (size_t)rgc * IMG_W + lane4;
        if (lv) {                                 // 18-20 lanes active
            gload16(ps, &B[sI][0]);               // p -> [0..79]
            gload16(ts, &B[sI][80]);              // t -> [80..159]
        }
    }

    // ---- counted wait: rows j+1..j+5 (10 loads) may stay in flight ----
    asm volatile("s_waitcnt vmcnt(10)" ::: "memory");

    // ---- horizontal 11-tap conv of p,t,p^2,t^2,pt + vertical scatter ----
    const int rgj = r0 - 5 + j;
    if (rgj >= 0 && rgj < IMG_H) {        // wave-uniform (r0, j uniform)
        const int sR = j & (RING - 1);
        const float* Lb = &B[sR][lane + 3];       // one base -> ds_read2
        v2f h01 = {0.f, 0.f};                     // {hp, ht}
        v2f h23 = {0.f, 0.f};                     // {hpp, htt}
        float hpt = 0.f;
        #pragma unroll
        for (int k = 0; k < 11; ++k) {
            const float w = G[k];
            const v2f wv = {w, w};
            v2f v;
            v.x = Lb[k];                          // p
            v.y = Lb[k + 80];                     // t   (read2 candidate)
            h01 = __builtin_elementwise_fma(wv, v, h01);     // pk_fma
            const v2f wab = wv * v;                          // pk_mul {wx,wy}
            h23 = __builtin_elementwise_fma(wab, v, h23);    // pk_fma
            hpt = fmaf(wab.x, v.y, hpt);                     // scalar fma
        }
        // vertical scatter: row j feeds outputs l = j-10..j, slot = l%11
#define SCAT(s) { constexpr int m = ((s) - PH + 21) % 11;                    \
                  constexpr float w = G[10 - m];                             \
                  const v2f wv = {w, w};                                     \
                  acc01[s] = __builtin_elementwise_fma(wv, h01, acc01[s]);   \
                  acc23[s] = __builtin_elementwise_fma(wv, h23, acc23[s]);   \
                  accpt[s] = fmaf(w, hpt, accpt[s]); }
        SCAT(0) SCAT(1) SCAT(2) SCAT(3) SCAT(4) SCAT(5)
        SCAT(6) SCAT(7) SCAT(8) SCAT(9) SCAT(10)
#undef SCAT
    }
    // (row-OOB: conv of zero rows contributes zero -> skip is identical.)

    // ---- emit completed output row l = j-10 (slot (PH+1)%11), then reset ----
    constexpr int SE = (PH + 1) % 11;
    const int l = j - 10;
    if (l >= 0 && l < TH) {                       // wave-uniform branch
        const float mp = acc01[SE].x, mt = acc01[SE].y;
        const float mpp = mp * mp, mtt = mt * mt, mpt = mp * mt;
        const float sp  = acc23[SE].x - mpp;
        const float st  = acc23[SE].y - mtt;
        const float spt = accpt[SE]   - mpt;
        const float num = (2.f * mpt + SSIM_C1) * (2.f * spt + SSIM_C2);
        const float den = (mpp + mtt + SSIM_C1) * (sp + st + SSIM_C2);
        lsum += num * __builtin_amdgcn_rcpf(den); // den >= C1*C2 > 0
    }
    acc01[SE] = (v2f){0.f, 0.f};
    acc23[SE] = (v2f){0.f, 0.f};
    accpt[SE] = 0.f;
}

__global__ __launch_bounds__(128, 6) void ssim_main(const float* __restrict__ pred,
                                                    const float* __restrict__ targ,
                                                    float* __restrict__ ws) {
    __shared__ float B[2][RING][LROW];    // [wave][slot][p|t]  = 10.0 KB
    __shared__ float wsum[2];

    const int tid  = threadIdx.x;
    const int lane = tid & 63;
    const int wid  = tid >> 6;

    // 12288 tiles = 8 col-strips x 16 row-bands x 96 planes; 2 waves/block.
    const int gt    = __builtin_amdgcn_readfirstlane(blockIdx.x * 2 + wid);
    const int c0    = (gt & 7) * 64;
    const int r0    = ((gt >> 3) & 15) * TH;
    const int plane = gt >> 7;
    // Window base: column c0-8 (16B-aligned since c0%64==0).
    const float* pplw = pred + (size_t)plane * (IMG_H * IMG_W) + (c0 - 8);
    const float* tplw = targ + (size_t)plane * (IMG_H * IMG_W) + (c0 - 8);

    float (*W)[LROW] = B[wid];

    // Lane covers window cols [4*lane, 4*lane+3] = global [c0-8+4*lane, +3].
    const int  lane4 = lane * 4;
    const int  gc0   = c0 - 8 + lane4;
    const bool lv    = (lane < 20) && (gc0 >= 0) && (gc0 <= IMG_W - 4);

    // Pre-zero LDS words of permanently masked lanes (edge strips only):
    // gload_lds never touches them, so they stay zero all kernel.
    if (lane < 20 && !lv) {
        #pragma unroll
        for (int s = 0; s < RING; ++s) {
            #pragma unroll
            for (int w = 0; w < 4; ++w) {
                W[s][lane4 + w]      = 0.f;       // p section
                W[s][80 + lane4 + w] = 0.f;       // t section
            }
        }
    }

    // Prologue: issue rows j=0..4 (global rows r0-5..r0-1, clamped) into
    // ring slots 0..4 = 10 VMEM ops.
    #pragma unroll
    for (int r = 0; r < 5; ++r) {
        const int rg  = max(r0 - 5 + r, 0);       // top clamp only (r0<=480)
        const float* ps = pplw + (size_t)rg * IMG_W + lane4;
        const float* ts = tplw + (size_t)rg * IMG_W + lane4;
        if (lv) {
            gload16(ps, &W[r][0]);
            gload16(ts, &W[r][80]);
        }
    }

    v2f   acc01[11];
    v2f   acc23[11];
    float accpt[11];
    #pragma unroll
    for (int s = 0; s < 11; ++s) {
        acc01[s] = (v2f){0.f, 0.f};
        acc23[s] = (v2f){0.f, 0.f};
        accpt[s] = 0.f;
    }

    float lsum = 0.f;

    // 42 phases: 3 chunks of 11 (j=0..32) + 9-phase tail (j=33..41).
    // Tail j0=33 keeps j%11 == PH so the SE/SCAT slot templates line up.
#define P(n) phase<n>(pplw, tplw, r0, j0, lane4, W, lane, lv, \
                      acc01, acc23, accpt, lsum);
    int j0 = 0;
    for (int c = 0; c < 3; ++c) {
        P(0) P(1) P(2) P(3) P(4) P(5) P(6) P(7) P(8) P(9) P(10)
        j0 += 11;
    }
    P(0) P(1) P(2) P(3) P(4) P(5) P(6) P(7) P(8)
#undef P

    // wave reduce -> one plain store per block into the workspace
    #pragma unroll
    for (int off = 32; off > 0; off >>= 1) lsum += __shfl_down(lsum, off);
    if (lane == 0) wsum[wid] = lsum;
    __syncthreads();
    if (tid == 0) ws[blockIdx.x] = wsum[0] + wsum[1];
}

__global__ __launch_bounds__(256) void ssim_finalize(const float* __restrict__ ws,
                                                     float* __restrict__ out) {
    __shared__ float wsum[4];
    const int tid  = threadIdx.x;
    const int lane = tid & 63;
    const int wid  = tid >> 6;
    float s = 0.f;
    #pragma unroll
    for (int i = 0; i < 24; ++i) s += ws[tid + 256 * i];   // 6144 = 24*256
    #pragma unroll
    for (int off = 32; off > 0; off >>= 1) s += __shfl_down(s, off);
    if (lane == 0) wsum[wid] = s;
    __syncthreads();
    if (tid == 0) {
        const float tot = wsum[0] + wsum[1] + wsum[2] + wsum[3];
        out[0] = 1.0f - tot * (1.0f / 25165824.0f);  // 1 - sum/(32*3*512*512)
    }
}

extern "C" void kernel_launch(void* const* d_in, const int* in_sizes, int n_in,
                              void* d_out, int out_size, void* d_ws, size_t ws_size,
                              hipStream_t stream) {
    (void)in_sizes; (void)n_in; (void)out_size; (void)ws_size;
    const float* pred = (const float*)d_in[0];
    const float* targ = (const float*)d_in[1];
    float* ws  = (float*)d_ws;          // 6144 floats of scratch (24 KB)
    float* out = (float*)d_out;

    ssim_main<<<dim3(6144), 128, 0, stream>>>(pred, targ, ws);
    ssim_finalize<<<1, 256, 0, stream>>>(ws, out);
}

// Round 11
// 248.611 us; speedup vs baseline: 1.5676x; 1.5676x over previous
//
#include <hip/hip_runtime.h>

// SSIM loss, fused single pass, barrier-free, spill-free.
// [32,3,512,512] fp32 = 96 planes of 512x512. Each WAVE owns a 64x64 tile.
// Round-16: round-10 EXACT base (best verified: 125us, absmax 0.0) + ONE
// change: the 11 tap-pair LDS reads are issued as a BATCH into registers
// (v2f vrow[11], full unroll) with a sched_barrier(0) fence before the
// conv consumes them.
// Rationale (round-10 counter arithmetic): per-wave issue 470cy/phase but
// per-wave elapsed ~2020cy/phase -> ~1550cy STALL per phase. VMEM is
// covered (distance-5 ring >> 900cy HBM); the magnitude matches 11 serial
// LDS latencies (read->use->read->use in the old CV loop, ~120cy each).
// Batch-issue + in-order DS completion = ONE ~120cy wait per phase.
// Round-15 (64x32 tiles, (128,6)): occupancy 39->57% as predicted but the
// 85-reg cap spilled (WRITE 334MB) -> 260us. Reg budget here: 55 acc + 22
// vrow + ~15 misc ~= 92 < 128 cap of (256,4); spill tripwire = WRITE_SIZE.
// Unchanged: 8-slot LDS ring, distance-5 prefetch, s_waitcnt vmcnt(10)
// (never 0), global_load_lds dwordx4 per-lane addr + uniform LDS dest,
// merged p|t slot (ds_read2 pairs at +0/+80), pk dual-f32 math, EXACT
// round-3 arithmetic and accumulation order.

#define IMG_H   512
#define IMG_W   512
#define TH      64          // tile rows/cols per wave
#define NCHUNK  7           // 7*11 = 77 row-phases (74 input rows needed)
#define LROW    160         // floats per LDS row-slot: p[0..79] | t[80..159]
#define RING    8           // ring slots (rows j..j+5 live)
#define SSIM_C1 1e-4f
#define SSIM_C2 9e-4f

typedef float v2f __attribute__((ext_vector_type(2)));

// Gaussian taps, sigma=1.5, window 11.
__device__ constexpr float G[11] = {
    0.00102838f, 0.00759879f, 0.03600078f, 0.10936070f, 0.21300563f,
    0.26601180f,
    0.21300563f, 0.10936070f, 0.03600078f, 0.00759879f, 0.00102838f
};

// Async 16B/lane global->LDS. Global addr is per-lane; LDS dest is
// wave-uniform base + lane*16 (m97/m104).
__device__ __forceinline__ void gload16(const float* g, float* l) {
    __builtin_amdgcn_global_load_lds(
        (const __attribute__((address_space(1))) float*)g,
        (__attribute__((address_space(3))) float*)l, 16, 0, 0);
}

template<int PH>
__device__ __forceinline__ void phase(const float* __restrict__ pplw,
                                      const float* __restrict__ tplw,
                                      int r0, int j0, int lane4,
                                      float (*B)[LROW],
                                      int lane, bool lv,
                                      v2f (&acc01)[11], v2f (&acc23)[11],
                                      float (&accpt)[11], float& lsum) {
    const int j = j0 + PH;

    // ---- issue async dwordx4 loads for row j+5 into ring slot (j+5)&7 ----
    // Row clamped so EVERY phase issues exactly 2 VMEM ops (vmcnt arithmetic
    // exact); clamped-row garbage never read (row-OOB phases skip conv).
    {
        const int rg  = r0 + j;                   // = (r0-5) + (j+5)
        const int rgc = min(max(rg, 0), IMG_H - 1);
        const int sI  = (j + 5) & (RING - 1);
        const float* ps = pplw + (size_t)rgc * IMG_W + lane4;  // per-lane
        const float* ts = tplw + (size_t)rgc * IMG_W + lane4;
        if (lv) {                                 // 18-20 lanes active
            gload16(ps, &B[sI][0]);               // p -> [0..79]
            gload16(ts, &B[sI][80]);              // t -> [80..159]
        }
    }

    // ---- counted wait: rows j+1..j+5 (10 loads) may stay in flight ----
    asm volatile("s_waitcnt vmcnt(10)" ::: "memory");

    // ---- horizontal 11-tap conv of p,t,p^2,t^2,pt + vertical scatter ----
    const int rgj = r0 - 5 + j;
    if (rgj >= 0 && rgj < IMG_H) {        // wave-uniform (r0, j uniform)
        const int sR = j & (RING - 1);
        const float* Lb = &B[sR][lane + 3];       // one base -> ds_read2

        // Stage 1: BATCH all 11 tap-pair reads into registers (static idx).
        v2f vrow[11];
        #pragma unroll
        for (int k = 0; k < 11; ++k) {
            v2f v;
            v.x = Lb[k];                          // p   (ds_read2_b32:
            v.y = Lb[k + 80];                     // t    offset0=k, off1=k+80)
            vrow[k] = v;
        }
        // Fence: no compute may be hoisted between/above the reads.
        __builtin_amdgcn_sched_barrier(0);

        // Stage 2: conv consumes registers only (one lgkm wait total).
        v2f h01 = {0.f, 0.f};                     // {hp, ht}
        v2f h23 = {0.f, 0.f};                     // {hpp, htt}
        float hpt = 0.f;
        #pragma unroll
        for (int k = 0; k < 11; ++k) {
            const float w = G[k];
            const v2f wv = {w, w};
            const v2f v = vrow[k];
            h01 = __builtin_elementwise_fma(wv, v, h01);     // pk_fma
            const v2f wab = wv * v;                          // pk_mul {wx,wy}
            h23 = __builtin_elementwise_fma(wab, v, h23);    // pk_fma
            hpt = fmaf(wab.x, v.y, hpt);                     // scalar fma
        }
        // vertical scatter: row j feeds outputs l = j-10..j, slot = l%11
#define SCAT(s) { constexpr int m = ((s) - PH + 21) % 11;                    \
                  constexpr float w = G[10 - m];                             \
                  const v2f wv = {w, w};                                     \
                  acc01[s] = __builtin_elementwise_fma(wv, h01, acc01[s]);   \
                  acc23[s] = __builtin_elementwise_fma(wv, h23, acc23[s]);   \
                  accpt[s] = fmaf(w, hpt, accpt[s]); }
        SCAT(0) SCAT(1) SCAT(2) SCAT(3) SCAT(4) SCAT(5)
        SCAT(6) SCAT(7) SCAT(8) SCAT(9) SCAT(10)
#undef SCAT
    }
    // (row-OOB: conv of zero rows contributes zero -> skip is identical.)

    // ---- emit completed output row l = j-10 (slot (PH+1)%11), then reset ----
    constexpr int SE = (PH + 1) % 11;
    const int l = j - 10;
    if (l >= 0 && l < TH) {                       // wave-uniform branch
        const float mp = acc01[SE].x, mt = acc01[SE].y;
        const float mpp = mp * mp, mtt = mt * mt, mpt = mp * mt;
        const float sp  = acc23[SE].x - mpp;
        const float st  = acc23[SE].y - mtt;
        const float spt = accpt[SE]   - mpt;
        const float num = (2.f * mpt + SSIM_C1) * (2.f * spt + SSIM_C2);
        const float den = (mpp + mtt + SSIM_C1) * (sp + st + SSIM_C2);
        lsum += num * __builtin_amdgcn_rcpf(den); // den >= C1*C2 > 0
    }
    acc01[SE] = (v2f){0.f, 0.f};
    acc23[SE] = (v2f){0.f, 0.f};
    accpt[SE] = 0.f;
}

__global__ __launch_bounds__(256, 4) void ssim_main(const float* __restrict__ pred,
                                                    const float* __restrict__ targ,
                                                    float* __restrict__ ws) {
    __shared__ float B[4][RING][LROW];    // [wave][slot][p|t]  = 20.0 KB
    __shared__ float wsum[4];

    const int tid  = threadIdx.x;
    const int lane = tid & 63;
    const int wid  = tid >> 6;

    // 6144 tiles = 8 col-strips x 8 row-bands x 96 planes; 4 waves/block.
    const int gt    = __builtin_amdgcn_readfirstlane(blockIdx.x * 4 + wid);
    const int c0    = (gt & 7) * TH;
    const int r0    = ((gt >> 3) & 7) * TH;
    const int plane = gt >> 6;
    // Window base: column c0-8 (16B-aligned since c0%64==0).
    const float* pplw = pred + (size_t)plane * (IMG_H * IMG_W) + (c0 - 8);
    const float* tplw = targ + (size_t)plane * (IMG_H * IMG_W) + (c0 - 8);

    float (*W)[LROW] = B[wid];

    // Lane covers window cols [4*lane, 4*lane+3] = global [c0-8+4*lane, +3].
    const int  lane4 = lane * 4;
    const int  gc0   = c0 - 8 + lane4;
    const bool lv    = (lane < 20) && (gc0 >= 0) && (gc0 <= IMG_W - 4);

    // Pre-zero LDS words of permanently masked lanes (edge strips only):
    // gload_lds never touches them, so they stay zero all kernel.
    if (lane < 20 && !lv) {
        #pragma unroll
        for (int s = 0; s < RING; ++s) {
            #pragma unroll
            for (int w = 0; w < 4; ++w) {
                W[s][lane4 + w]      = 0.f;       // p section
                W[s][80 + lane4 + w] = 0.f;       // t section
            }
        }
    }

    // Prologue: issue rows j=0..4 (global rows r0-5..r0-1, clamped) into
    // ring slots 0..4 = 10 VMEM ops.
    #pragma unroll
    for (int r = 0; r < 5; ++r) {
        const int rg  = max(r0 - 5 + r, 0);       // top clamp only (r0<=448)
        const float* ps = pplw + (size_t)rg * IMG_W + lane4;
        const float* ts = tplw + (size_t)rg * IMG_W + lane4;
        if (lv) {
            gload16(ps, &W[r][0]);
            gload16(ts, &W[r][80]);
        }
    }

    v2f   acc01[11];
    v2f   acc23[11];
    float accpt[11];
    #pragma unroll
    for (int s = 0; s < 11; ++s) {
        acc01[s] = (v2f){0.f, 0.f};
        acc23[s] = (v2f){0.f, 0.f};
        accpt[s] = 0.f;
    }

    float lsum = 0.f;

    for (int chunk = 0; chunk < NCHUNK; ++chunk) {
        const int j0 = chunk * 11;
#define P(n) phase<n>(pplw, tplw, r0, j0, lane4, W, lane, lv, \
                      acc01, acc23, accpt, lsum);
        P(0) P(1) P(2) P(3) P(4) P(5) P(6) P(7) P(8) P(9) P(10)
#undef P
    }

    // wave reduce -> one plain store per block into the workspace
    #pragma unroll
    for (int off = 32; off > 0; off >>= 1) lsum += __shfl_down(lsum, off);
    if (lane == 0) wsum[wid] = lsum;
    __syncthreads();
    if (tid == 0) ws[blockIdx.x] = wsum[0] + wsum[1] + wsum[2] + wsum[3];
}

__global__ __launch_bounds__(256) void ssim_finalize(const float* __restrict__ ws,
                                                     float* __restrict__ out) {
    __shared__ float wsum[4];
    const int tid  = threadIdx.x;
    const int lane = tid & 63;
    const int wid  = tid >> 6;
    float s = 0.f;
    #pragma unroll
    for (int i = 0; i < 6; ++i) s += ws[tid + 256 * i];   // 1536 = 6*256
    #pragma unroll
    for (int off = 32; off > 0; off >>= 1) s += __shfl_down(s, off);
    if (lane == 0) wsum[wid] = s;
    __syncthreads();
    if (tid == 0) {
        const float tot = wsum[0] + wsum[1] + wsum[2] + wsum[3];
        out[0] = 1.0f - tot * (1.0f / 25165824.0f);  // 1 - sum/(32*3*512*512)
    }
}

extern "C" void kernel_launch(void* const* d_in, const int* in_sizes, int n_in,
                              void* d_out, int out_size, void* d_ws, size_t ws_size,
                              hipStream_t stream) {
    (void)in_sizes; (void)n_in; (void)out_size; (void)ws_size;
    const float* pred = (const float*)d_in[0];
    const float* targ = (const float*)d_in[1];
    float* ws  = (float*)d_ws;          // 1536 floats of scratch
    float* out = (float*)d_out;

    ssim_main<<<dim3(1536), 256, 0, stream>>>(pred, targ, ws);
    ssim_finalize<<<1, 256, 0, stream>>>(ws, out);
}